// Round 15
// baseline (1270.003 us; speedup 1.0000x reference)
//
#include <hip/hip_runtime.h>
#include <math.h>

#define ND 256
#define RPB 64            // rows per block (64 | 576 via 4608 blocks)
#define RPW 8             // rows per wave (8 waves, 512 threads)
#define ROWS_PER_B 576
#define BATCH 512
#define NBLOCKS (BATCH * ROWS_PER_B / RPB)   // 4608
#define YSTR 260          // sY row stride: 1040B, 16B-aligned, head 8-way not 32-way

// itertools.permutations(range(4)) — lexicographic order, with parity signs
__constant__ int c_P[24 * 4] = {
    0,1,2,3, 0,1,3,2, 0,2,1,3, 0,2,3,1, 0,3,1,2, 0,3,2,1,
    1,0,2,3, 1,0,3,2, 1,2,0,3, 1,2,3,0, 1,3,0,2, 1,3,2,0,
    2,0,1,3, 2,0,3,1, 2,1,0,3, 2,1,3,0, 2,3,0,1, 2,3,1,0,
    3,0,1,2, 3,0,2,1, 3,1,0,2, 3,1,2,0, 3,2,0,1, 3,2,1,0
};
__constant__ float c_S[24] = {
     1.f,-1.f,-1.f, 1.f, 1.f,-1.f,
    -1.f, 1.f, 1.f,-1.f,-1.f, 1.f,
     1.f,-1.f,-1.f, 1.f, 1.f,-1.f,
    -1.f, 1.f, 1.f,-1.f,-1.f, 1.f
};

// Structure (r15 = r11's per-wave stream, repacked as 512-thread blocks):
//  * 8 waves/block, RPW=8, RPB=64 -> LDS 67,584 B; 2 blocks/CU fits with
//    margin (even at 8 KB rounding: 144 KB <= 160 KB) -> 16 waves/CU =
//    4 waves/SIMD, the highest TLP of any round. r14 falsified the fine-
//    grained LDS-quantum model (38.9 KB still 2 blocks); this packing does
//    not ride an allocation boundary.
//  * W streams DIRECTLY from global/L2, one-step register ping-pong; no
//    K-loop barriers (2 __syncthreads total). Halved block count (4608)
//    halves W L2 re-read traffic.
//  * Y in LDS, read via UNIFORM ds_read_b128 (broadcast, zero VALU);
//    YSTR=260 padding (r13's XOR swizzle regression reverted for good).
//  fp32 fmaf chain order bit-identical to passing r7-r14 (absmax 0.125).
__global__ __launch_bounds__(512, 2)
void fused_resnet(const float* __restrict__ x1, const float* __restrict__ x2,
                  const float* __restrict__ W0, const float* __restrict__ b0,
                  const float* __restrict__ W1, const float* __restrict__ b1,
                  const float* __restrict__ W2, const float* __restrict__ b2,
                  const float* __restrict__ Wf, const float* __restrict__ bf,
                  double* __restrict__ anti)
{
    __shared__ __align__(16) float smem[16896];  // 67,584 B -> 2 blocks/CU
    float* sWf = smem;            // [256] head weights
    float* sY  = smem + 256;      // [64][260] f32 activations (wave-private rows)
    // L0 feats occupy sY[row*YSTR + 0..23] until overwritten by y0.

    const int t    = threadIdx.x;
    const int lane = t & 63;
    const int wv   = t >> 6;          // wave 0..7
    const int r0   = wv * RPW;        // this wave's first row
    const int gr0  = blockIdx.x * RPB;
    const int b    = gr0 / ROWS_PER_B;

    // ---- feats into sY cols 0..23; Wf into sWf ----
    for (int i = t; i < RPB * 24; i += 512) {
        int lr = i / 24, c = i % 24;
        int pp = (gr0 + lr) % ROWS_PER_B;
        float v;
        if (c < 12) {
            v = x1[b * 12 + c_P[(pp / 24) * 4 + c / 3] * 3 + (c % 3)];
        } else {
            int cc = c - 12;
            v = x2[b * 12 + c_P[(pp % 24) * 4 + cc / 3] * 3 + (cc % 3)];
        }
        sY[lr * YSTR + c] = v;
    }
    if (t < 64) ((float4*)sWf)[t] = ((const float4*)Wf)[t];
    __syncthreads();                  // barrier #1

    float acc[RPW][4];   // this lane's cols 4*lane..4*lane+3 of its wave's rows

    // ---------- layer 0: 24 -> 256, tanh, no residual (W0 direct) ----------
    #pragma unroll
    for (int r = 0; r < RPW; ++r) { acc[r][0]=0.f; acc[r][1]=0.f; acc[r][2]=0.f; acc[r][3]=0.f; }
    #pragma unroll 1
    for (int j = 0; j < 6; ++j) {     // K rows 4j..4j+3
        const float4* p = (const float4*)W0 + j * 256 + lane;
        float4 w0 = p[0], w1 = p[64], w2 = p[128], w3 = p[192];
        #pragma unroll
        for (int r = 0; r < RPW; ++r) {
            float4 yv = *(const float4*)&sY[(r0 + r) * YSTR + j * 4];   // uniform (feats)
            acc[r][0] = fmaf(yv.x, w0.x, acc[r][0]);
            acc[r][1] = fmaf(yv.x, w0.y, acc[r][1]);
            acc[r][2] = fmaf(yv.x, w0.z, acc[r][2]);
            acc[r][3] = fmaf(yv.x, w0.w, acc[r][3]);
            acc[r][0] = fmaf(yv.y, w1.x, acc[r][0]);
            acc[r][1] = fmaf(yv.y, w1.y, acc[r][1]);
            acc[r][2] = fmaf(yv.y, w1.z, acc[r][2]);
            acc[r][3] = fmaf(yv.y, w1.w, acc[r][3]);
            acc[r][0] = fmaf(yv.z, w2.x, acc[r][0]);
            acc[r][1] = fmaf(yv.z, w2.y, acc[r][1]);
            acc[r][2] = fmaf(yv.z, w2.z, acc[r][2]);
            acc[r][3] = fmaf(yv.z, w2.w, acc[r][3]);
            acc[r][0] = fmaf(yv.w, w3.x, acc[r][0]);
            acc[r][1] = fmaf(yv.w, w3.y, acc[r][1]);
            acc[r][2] = fmaf(yv.w, w3.z, acc[r][2]);
            acc[r][3] = fmaf(yv.w, w3.w, acc[r][3]);
        }
    }
    {
        float4 bv = *(const float4*)&b0[4 * lane];
        #pragma unroll
        for (int r = 0; r < RPW; ++r) {
            float4 o;
            o.x = tanhf(acc[r][0] + bv.x);
            o.y = tanhf(acc[r][1] + bv.y);
            o.z = tanhf(acc[r][2] + bv.z);
            o.w = tanhf(acc[r][3] + bv.w);
            *(float4*)&sY[(r0 + r) * YSTR + 4 * lane] = o;   // wave-private rows
        }
    }

    // ---------- layers 1,2: 256 -> 256, tanh + residual (W direct) --------
    #pragma unroll 1
    for (int L = 0; L < 2; ++L) {
        const float* __restrict__ Wg = L ? W2 : W1;
        const float* __restrict__ bp = L ? b2 : b1;
        const float4* pw = (const float4*)Wg + lane;
        #pragma unroll
        for (int r = 0; r < RPW; ++r) { acc[r][0]=0.f; acc[r][1]=0.f; acc[r][2]=0.f; acc[r][3]=0.f; }

        float4 wA0 = pw[0], wA1 = pw[64], wA2 = pw[128], wA3 = pw[192];
        float4 wB0, wB1, wB2, wB3;
        #pragma unroll 1
        for (int j = 0; j < 64; j += 2) {
            {   // prefetch j+1
                const float4* p = pw + (j + 1) * 256;
                wB0 = p[0]; wB1 = p[64]; wB2 = p[128]; wB3 = p[192];
            }
            #pragma unroll
            for (int r = 0; r < RPW; ++r) {
                float4 yv = *(const float4*)&sY[(r0 + r) * YSTR + j * 4];  // uniform
                acc[r][0] = fmaf(yv.x, wA0.x, acc[r][0]);
                acc[r][1] = fmaf(yv.x, wA0.y, acc[r][1]);
                acc[r][2] = fmaf(yv.x, wA0.z, acc[r][2]);
                acc[r][3] = fmaf(yv.x, wA0.w, acc[r][3]);
                acc[r][0] = fmaf(yv.y, wA1.x, acc[r][0]);
                acc[r][1] = fmaf(yv.y, wA1.y, acc[r][1]);
                acc[r][2] = fmaf(yv.y, wA1.z, acc[r][2]);
                acc[r][3] = fmaf(yv.y, wA1.w, acc[r][3]);
                acc[r][0] = fmaf(yv.z, wA2.x, acc[r][0]);
                acc[r][1] = fmaf(yv.z, wA2.y, acc[r][1]);
                acc[r][2] = fmaf(yv.z, wA2.z, acc[r][2]);
                acc[r][3] = fmaf(yv.z, wA2.w, acc[r][3]);
                acc[r][0] = fmaf(yv.w, wA3.x, acc[r][0]);
                acc[r][1] = fmaf(yv.w, wA3.y, acc[r][1]);
                acc[r][2] = fmaf(yv.w, wA3.z, acc[r][2]);
                acc[r][3] = fmaf(yv.w, wA3.w, acc[r][3]);
            }
            if (j + 2 < 64) {   // prefetch j+2
                const float4* p = pw + (j + 2) * 256;
                wA0 = p[0]; wA1 = p[64]; wA2 = p[128]; wA3 = p[192];
            }
            #pragma unroll
            for (int r = 0; r < RPW; ++r) {
                float4 yv = *(const float4*)&sY[(r0 + r) * YSTR + j * 4 + 4]; // uniform
                acc[r][0] = fmaf(yv.x, wB0.x, acc[r][0]);
                acc[r][1] = fmaf(yv.x, wB0.y, acc[r][1]);
                acc[r][2] = fmaf(yv.x, wB0.z, acc[r][2]);
                acc[r][3] = fmaf(yv.x, wB0.w, acc[r][3]);
                acc[r][0] = fmaf(yv.y, wB1.x, acc[r][0]);
                acc[r][1] = fmaf(yv.y, wB1.y, acc[r][1]);
                acc[r][2] = fmaf(yv.y, wB1.z, acc[r][2]);
                acc[r][3] = fmaf(yv.y, wB1.w, acc[r][3]);
                acc[r][0] = fmaf(yv.z, wB2.x, acc[r][0]);
                acc[r][1] = fmaf(yv.z, wB2.y, acc[r][1]);
                acc[r][2] = fmaf(yv.z, wB2.z, acc[r][2]);
                acc[r][3] = fmaf(yv.z, wB2.w, acc[r][3]);
                acc[r][0] = fmaf(yv.w, wB3.x, acc[r][0]);
                acc[r][1] = fmaf(yv.w, wB3.y, acc[r][1]);
                acc[r][2] = fmaf(yv.w, wB3.z, acc[r][2]);
                acc[r][3] = fmaf(yv.w, wB3.w, acc[r][3]);
            }
        }
        float4 bv = *(const float4*)&bp[4 * lane];
        #pragma unroll
        for (int r = 0; r < RPW; ++r) {
            float4 yo = *(const float4*)&sY[(r0 + r) * YSTR + 4 * lane];  // residual
            float4 o;
            o.x = tanhf(acc[r][0] + bv.x) + yo.x;
            o.y = tanhf(acc[r][1] + bv.y) + yo.y;
            o.z = tanhf(acc[r][2] + bv.z) + yo.z;
            o.w = tanhf(acc[r][3] + bv.w) + yo.w;
            *(float4*)&sY[(r0 + r) * YSTR + 4 * lane] = o;   // wave-private rows
        }
    }

    // ---------- head: per-row fp32 chain from sY, f64 signed sum ----------
    __syncthreads();                  // barrier #2: cross-wave row reads below
    double contrib = 0.0;
    if (t < RPB) {                    // rows 0..63 handled by wave 0's lanes
        const float* yrow = &sY[t * YSTR];
        float f = 0.f;
        #pragma unroll 8
        for (int k = 0; k < ND; ++k) f = fmaf(yrow[k], sWf[k], f);
        f += bf[0];
        int pp = (gr0 + t) % ROWS_PER_B;
        contrib = (double)(c_S[pp / 24] * c_S[pp % 24]) * (double)f;
    }
    if (wv == 0) {
        #pragma unroll
        for (int off = 32; off > 0; off >>= 1) contrib += __shfl_xor(contrib, off, 64);
        if (lane == 0) atomicAdd(&anti[b], contrib);
    }
}

__global__ void finalize_log(const double* __restrict__ anti, float* __restrict__ out) {
    int i = blockIdx.x * 256 + threadIdx.x;
    if (i < BATCH) out[i] = (float)log(fabs(anti[i]));
}

extern "C" void kernel_launch(void* const* d_in, const int* in_sizes, int n_in,
                              void* d_out, int out_size, void* d_ws, size_t ws_size,
                              hipStream_t stream) {
    const float* x1 = (const float*)d_in[0];
    const float* x2 = (const float*)d_in[1];
    const float* W0 = (const float*)d_in[2];
    const float* b0 = (const float*)d_in[3];
    const float* W1 = (const float*)d_in[4];
    const float* b1 = (const float*)d_in[5];
    const float* W2 = (const float*)d_in[6];
    const float* b2 = (const float*)d_in[7];
    const float* Wf = (const float*)d_in[8];
    const float* bf = (const float*)d_in[9];
    double* anti = (double*)d_ws;                   // 512 doubles of scratch
    float* out   = (float*)d_out;

    (void)hipMemsetAsync(anti, 0, BATCH * sizeof(double), stream);
    fused_resnet<<<NBLOCKS, 512, 0, stream>>>(x1, x2, W0, b0, W1, b1, W2, b2, Wf, bf, anti);
    finalize_log<<<(BATCH + 255) / 256, 256, 0, stream>>>(anti, out);
}

// Round 16
// 1111.584 us; speedup vs baseline: 1.1425x; 1.1425x over previous
//
#include <hip/hip_runtime.h>
#include <math.h>

#define ND 256
#define RPB 48            // rows per block (48 | 576 via 6144 blocks)
#define RPW 12            // rows per wave (4 waves)
#define ROWS_PER_B 576
#define BATCH 512
#define NBLOCKS (BATCH * ROWS_PER_B / RPB)   // 6144
#define YSTR 260          // sY row stride: 1040B, 16B-aligned, head 4-way not 32-way

// itertools.permutations(range(4)) — lexicographic order, with parity signs
__constant__ int c_P[24 * 4] = {
    0,1,2,3, 0,1,3,2, 0,2,1,3, 0,2,3,1, 0,3,1,2, 0,3,2,1,
    1,0,2,3, 1,0,3,2, 1,2,0,3, 1,2,3,0, 1,3,0,2, 1,3,2,0,
    2,0,1,3, 2,0,3,1, 2,1,0,3, 2,1,3,0, 2,3,0,1, 2,3,1,0,
    3,0,1,2, 3,0,2,1, 3,1,0,2, 3,1,2,0, 3,2,0,1, 3,2,1,0
};
__constant__ float c_S[24] = {
     1.f,-1.f,-1.f, 1.f, 1.f,-1.f,
    -1.f, 1.f, 1.f,-1.f,-1.f, 1.f,
     1.f,-1.f,-1.f, 1.f, 1.f,-1.f,
    -1.f, 1.f, 1.f,-1.f,-1.f, 1.f
};

// FINAL (restoration of round-12, the best harness-verified variant: 1154 µs).
// Session findings pinned in this structure:
//  * fp32-VALU only: every MFMA path (fp16x2/x3 split, exact i8-digit) fails
//    the harness threshold — the antisymmetrized sum demands np's f32
//    sequential-FMA rounding order, not minimal true error (r2-r4).
//  * Y in LDS, wave-private rows, read via UNIFORM ds_read_b128 -> hardware
//    broadcast, zero VALU cost (r8); readlane broadcast costs 23% VALU (r7).
//  * W streams DIRECTLY from global/L2 with one-step register ping-pong; no
//    K-loop barriers, no LDS W staging (r10); 2 __syncthreads total.
//  * RPW=12 amortizes W-load/addr over 192 FMAs/k4-step (r12).
//  * launch_bounds(256,2): (256,3)/(256,4) caps provoke 0.5-1.2 GB scratch
//    spill (r5/r9/r10); live set ~104 VGPR must stay under the 128 cliff (r6).
//  * YSTR=260 padding; XOR swizzle regressed (r13: +6.3M conflicts, VGPR 128).
//  * Occupancy knobs exhausted: 8KB/40KB-quantum and 512-thread packings all
//    falsified (r13/r14/r15) — 2 blocks/CU at this LDS size is the floor the
//    allocator gives; VALUBusy 82% * lowest-work stream = best wall-clock.
__global__ __launch_bounds__(256, 2)
void fused_resnet(const float* __restrict__ x1, const float* __restrict__ x2,
                  const float* __restrict__ W0, const float* __restrict__ b0,
                  const float* __restrict__ W1, const float* __restrict__ b1,
                  const float* __restrict__ W2, const float* __restrict__ b2,
                  const float* __restrict__ Wf, const float* __restrict__ bf,
                  double* __restrict__ anti)
{
    __shared__ __align__(16) float smem[12736];  // 50,944 B
    float* sWf = smem;            // [256] head weights
    float* sY  = smem + 256;      // [48][260] f32 activations (wave-private rows)
    // L0 feats occupy sY[row*YSTR + 0..23] until overwritten by y0.

    const int t    = threadIdx.x;
    const int lane = t & 63;
    const int wv   = t >> 6;          // wave 0..3
    const int r0   = wv * RPW;        // this wave's first row
    const int gr0  = blockIdx.x * RPB;
    const int b    = gr0 / ROWS_PER_B;

    // ---- feats into sY cols 0..23; Wf into sWf ----
    for (int i = t; i < RPB * 24; i += 256) {
        int lr = i / 24, c = i % 24;
        int pp = (gr0 + lr) % ROWS_PER_B;
        float v;
        if (c < 12) {
            v = x1[b * 12 + c_P[(pp / 24) * 4 + c / 3] * 3 + (c % 3)];
        } else {
            int cc = c - 12;
            v = x2[b * 12 + c_P[(pp % 24) * 4 + cc / 3] * 3 + (cc % 3)];
        }
        sY[lr * YSTR + c] = v;
    }
    if (t < 64) ((float4*)sWf)[t] = ((const float4*)Wf)[t];
    __syncthreads();                  // barrier #1

    float acc[RPW][4];   // this lane's cols 4*lane..4*lane+3 of its wave's rows

    // ---------- layer 0: 24 -> 256, tanh, no residual (W0 direct) ----------
    #pragma unroll
    for (int r = 0; r < RPW; ++r) { acc[r][0]=0.f; acc[r][1]=0.f; acc[r][2]=0.f; acc[r][3]=0.f; }
    #pragma unroll 1
    for (int j = 0; j < 6; ++j) {     // K rows 4j..4j+3
        const float4* p = (const float4*)W0 + j * 256 + lane;
        float4 w0 = p[0], w1 = p[64], w2 = p[128], w3 = p[192];
        #pragma unroll
        for (int r = 0; r < RPW; ++r) {
            float4 yv = *(const float4*)&sY[(r0 + r) * YSTR + j * 4];   // uniform (feats)
            acc[r][0] = fmaf(yv.x, w0.x, acc[r][0]);
            acc[r][1] = fmaf(yv.x, w0.y, acc[r][1]);
            acc[r][2] = fmaf(yv.x, w0.z, acc[r][2]);
            acc[r][3] = fmaf(yv.x, w0.w, acc[r][3]);
            acc[r][0] = fmaf(yv.y, w1.x, acc[r][0]);
            acc[r][1] = fmaf(yv.y, w1.y, acc[r][1]);
            acc[r][2] = fmaf(yv.y, w1.z, acc[r][2]);
            acc[r][3] = fmaf(yv.y, w1.w, acc[r][3]);
            acc[r][0] = fmaf(yv.z, w2.x, acc[r][0]);
            acc[r][1] = fmaf(yv.z, w2.y, acc[r][1]);
            acc[r][2] = fmaf(yv.z, w2.z, acc[r][2]);
            acc[r][3] = fmaf(yv.z, w2.w, acc[r][3]);
            acc[r][0] = fmaf(yv.w, w3.x, acc[r][0]);
            acc[r][1] = fmaf(yv.w, w3.y, acc[r][1]);
            acc[r][2] = fmaf(yv.w, w3.z, acc[r][2]);
            acc[r][3] = fmaf(yv.w, w3.w, acc[r][3]);
        }
    }
    {
        float4 bv = *(const float4*)&b0[4 * lane];
        #pragma unroll
        for (int r = 0; r < RPW; ++r) {
            float4 o;
            o.x = tanhf(acc[r][0] + bv.x);
            o.y = tanhf(acc[r][1] + bv.y);
            o.z = tanhf(acc[r][2] + bv.z);
            o.w = tanhf(acc[r][3] + bv.w);
            *(float4*)&sY[(r0 + r) * YSTR + 4 * lane] = o;   // wave-private rows
        }
    }

    // ---------- layers 1,2: 256 -> 256, tanh + residual (W direct) --------
    #pragma unroll 1
    for (int L = 0; L < 2; ++L) {
        const float* __restrict__ Wg = L ? W2 : W1;
        const float* __restrict__ bp = L ? b2 : b1;
        const float4* pw = (const float4*)Wg + lane;
        #pragma unroll
        for (int r = 0; r < RPW; ++r) { acc[r][0]=0.f; acc[r][1]=0.f; acc[r][2]=0.f; acc[r][3]=0.f; }

        float4 wA0 = pw[0], wA1 = pw[64], wA2 = pw[128], wA3 = pw[192];
        float4 wB0, wB1, wB2, wB3;
        #pragma unroll 1
        for (int j = 0; j < 64; j += 2) {
            {   // prefetch j+1
                const float4* p = pw + (j + 1) * 256;
                wB0 = p[0]; wB1 = p[64]; wB2 = p[128]; wB3 = p[192];
            }
            #pragma unroll
            for (int r = 0; r < RPW; ++r) {
                float4 yv = *(const float4*)&sY[(r0 + r) * YSTR + j * 4];  // uniform
                acc[r][0] = fmaf(yv.x, wA0.x, acc[r][0]);
                acc[r][1] = fmaf(yv.x, wA0.y, acc[r][1]);
                acc[r][2] = fmaf(yv.x, wA0.z, acc[r][2]);
                acc[r][3] = fmaf(yv.x, wA0.w, acc[r][3]);
                acc[r][0] = fmaf(yv.y, wA1.x, acc[r][0]);
                acc[r][1] = fmaf(yv.y, wA1.y, acc[r][1]);
                acc[r][2] = fmaf(yv.y, wA1.z, acc[r][2]);
                acc[r][3] = fmaf(yv.y, wA1.w, acc[r][3]);
                acc[r][0] = fmaf(yv.z, wA2.x, acc[r][0]);
                acc[r][1] = fmaf(yv.z, wA2.y, acc[r][1]);
                acc[r][2] = fmaf(yv.z, wA2.z, acc[r][2]);
                acc[r][3] = fmaf(yv.z, wA2.w, acc[r][3]);
                acc[r][0] = fmaf(yv.w, wA3.x, acc[r][0]);
                acc[r][1] = fmaf(yv.w, wA3.y, acc[r][1]);
                acc[r][2] = fmaf(yv.w, wA3.z, acc[r][2]);
                acc[r][3] = fmaf(yv.w, wA3.w, acc[r][3]);
            }
            if (j + 2 < 64) {   // prefetch j+2
                const float4* p = pw + (j + 2) * 256;
                wA0 = p[0]; wA1 = p[64]; wA2 = p[128]; wA3 = p[192];
            }
            #pragma unroll
            for (int r = 0; r < RPW; ++r) {
                float4 yv = *(const float4*)&sY[(r0 + r) * YSTR + j * 4 + 4]; // uniform
                acc[r][0] = fmaf(yv.x, wB0.x, acc[r][0]);
                acc[r][1] = fmaf(yv.x, wB0.y, acc[r][1]);
                acc[r][2] = fmaf(yv.x, wB0.z, acc[r][2]);
                acc[r][3] = fmaf(yv.x, wB0.w, acc[r][3]);
                acc[r][0] = fmaf(yv.y, wB1.x, acc[r][0]);
                acc[r][1] = fmaf(yv.y, wB1.y, acc[r][1]);
                acc[r][2] = fmaf(yv.y, wB1.z, acc[r][2]);
                acc[r][3] = fmaf(yv.y, wB1.w, acc[r][3]);
                acc[r][0] = fmaf(yv.z, wB2.x, acc[r][0]);
                acc[r][1] = fmaf(yv.z, wB2.y, acc[r][1]);
                acc[r][2] = fmaf(yv.z, wB2.z, acc[r][2]);
                acc[r][3] = fmaf(yv.z, wB2.w, acc[r][3]);
                acc[r][0] = fmaf(yv.w, wB3.x, acc[r][0]);
                acc[r][1] = fmaf(yv.w, wB3.y, acc[r][1]);
                acc[r][2] = fmaf(yv.w, wB3.z, acc[r][2]);
                acc[r][3] = fmaf(yv.w, wB3.w, acc[r][3]);
            }
        }
        float4 bv = *(const float4*)&bp[4 * lane];
        #pragma unroll
        for (int r = 0; r < RPW; ++r) {
            float4 yo = *(const float4*)&sY[(r0 + r) * YSTR + 4 * lane];  // residual
            float4 o;
            o.x = tanhf(acc[r][0] + bv.x) + yo.x;
            o.y = tanhf(acc[r][1] + bv.y) + yo.y;
            o.z = tanhf(acc[r][2] + bv.z) + yo.z;
            o.w = tanhf(acc[r][3] + bv.w) + yo.w;
            *(float4*)&sY[(r0 + r) * YSTR + 4 * lane] = o;   // wave-private rows
        }
    }

    // ---------- head: per-row fp32 chain from sY, f64 signed sum ----------
    __syncthreads();                  // barrier #2: cross-wave row reads below
    double contrib = 0.0;
    if (t < RPB) {
        const float* yrow = &sY[t * YSTR];
        float f = 0.f;
        #pragma unroll 8
        for (int k = 0; k < ND; ++k) f = fmaf(yrow[k], sWf[k], f);
        f += bf[0];
        int pp = (gr0 + t) % ROWS_PER_B;
        contrib = (double)(c_S[pp / 24] * c_S[pp % 24]) * (double)f;
    }
    if (wv == 0) {   // rows 0..47 all live in wave 0 lanes 0..47
        #pragma unroll
        for (int off = 32; off > 0; off >>= 1) contrib += __shfl_xor(contrib, off, 64);
        if (lane == 0) atomicAdd(&anti[b], contrib);
    }
}

__global__ void finalize_log(const double* __restrict__ anti, float* __restrict__ out) {
    int i = blockIdx.x * 256 + threadIdx.x;
    if (i < BATCH) out[i] = (float)log(fabs(anti[i]));
}

extern "C" void kernel_launch(void* const* d_in, const int* in_sizes, int n_in,
                              void* d_out, int out_size, void* d_ws, size_t ws_size,
                              hipStream_t stream) {
    const float* x1 = (const float*)d_in[0];
    const float* x2 = (const float*)d_in[1];
    const float* W0 = (const float*)d_in[2];
    const float* b0 = (const float*)d_in[3];
    const float* W1 = (const float*)d_in[4];
    const float* b1 = (const float*)d_in[5];
    const float* W2 = (const float*)d_in[6];
    const float* b2 = (const float*)d_in[7];
    const float* Wf = (const float*)d_in[8];
    const float* bf = (const float*)d_in[9];
    double* anti = (double*)d_ws;                   // 512 doubles of scratch
    float* out   = (float*)d_out;

    (void)hipMemsetAsync(anti, 0, BATCH * sizeof(double), stream);
    fused_resnet<<<NBLOCKS, 256, 0, stream>>>(x1, x2, W0, b0, W1, b1, W2, b2, Wf, bf, anti);
    finalize_log<<<(BATCH + 255) / 256, 256, 0, stream>>>(anti, out);
}